// Round 3
// baseline (300.633 us; speedup 1.0000x reference)
//
#include <hip/hip_runtime.h>

#define THREADS 256
#define QPT 4              // queries per thread (2 float2 packs)
#define Q2  (QPT / 2)
#define SLICES 32
#define NPTS 8192
#define BATCH 4
#define SLICE (NPTS / SLICES)   // 256 targets per block
#define TG 4                    // targets per inner group
#define NGRP (SLICE / TG)       // 64
#define NMINS (2 * BATCH * NPTS)            // 65536
#define NBLOCKS ((NPTS / (THREADS * QPT)) * SLICES * 2 * BATCH)  // 8*32*8 = 2048

typedef float f2 __attribute__((ext_vector_type(2)));

// ws layout: [2][BATCH][NPTS] uint min arrays (256 KB) + 1 uint ticket counter

__global__ void chamfer_init(unsigned int* mins, unsigned int* counter, float* out) {
    int i = blockIdx.x * blockDim.x + threadIdx.x;
    mins[i] = 0x7F800000u;  // +inf
    if (i == 0) {
        if (counter) *counter = 0u;
        else out[0] = 0.0f;
    }
}

__global__ __launch_bounds__(THREADS, 4) void chamfer_main(
    const float* __restrict__ p1, const float* __restrict__ p2,
    unsigned int* __restrict__ mins, unsigned int* __restrict__ counter,
    float* __restrict__ out)
{
    const int tid  = threadIdx.x;
    const int bz   = blockIdx.z;         // 0..7 : dir*4 + batch
    const int dir  = bz >> 2;
    const int b    = bz & 3;
    const int qbase = blockIdx.x * (THREADS * QPT);
    const int tbase = blockIdx.y * SLICE;

    const float* __restrict__ qsrc = (dir == 0) ? p1 : p2;
    const float* __restrict__ tsrc = (dir == 0) ? p2 : p1;

    // ---- queries: fold the -2 into the query registers: s* = -2*q* ----
    f2 sx[Q2], sy[Q2], sz[Q2], best[Q2];
#pragma unroll
    for (int j = 0; j < Q2; ++j) {
        const int qa = qbase + (2 * j + 0) * THREADS + tid;
        const int qb = qbase + (2 * j + 1) * THREADS + tid;
        const float* pa = qsrc + ((size_t)b * NPTS + qa) * 3;
        const float* pb = qsrc + ((size_t)b * NPTS + qb) * 3;
        sx[j] = f2{-2.0f * pa[0], -2.0f * pb[0]};
        sy[j] = f2{-2.0f * pa[1], -2.0f * pb[1]};
        sz[j] = f2{-2.0f * pa[2], -2.0f * pb[2]};
        best[j] = f2{3.0e38f, 3.0e38f};
    }

    // ---- target base address, laundered through a VGPR so loads stay vector
    // (uniform-address global_load_dwordx2 -> one 8B L2 request, broadcast) ----
    int zoff;
    asm("v_mov_b32 %0, 0" : "=v"(zoff));
    const float* tbp = tsrc + ((size_t)b * NPTS + tbase) * 3 + zoff;

    // ---- main loop: 4 targets per group, 6 dwordx2 loads land directly in
    // register pairs; |t|^2 computed on the fly; op_sel broadcasts from pairs.
    // pairs: P0=(x0,y0) P1=(z0,x1) P2=(y1,z1) P3=(x2,y2) P4=(z2,x3) P5=(y3,z3)
#pragma unroll 2
    for (int g = 0; g < NGRP; ++g) {
        const f2* gp = (const f2*)(tbp + 12 * g);
        f2 P0 = gp[0], P1 = gp[1], P2 = gp[2], P3 = gp[3], P4 = gp[4], P5 = gp[5];
        float w0 = fmaf(P0.x, P0.x, fmaf(P0.y, P0.y, P1.x * P1.x));
        float w1 = fmaf(P1.y, P1.y, fmaf(P2.x, P2.x, P2.y * P2.y));
        float w2 = fmaf(P3.x, P3.x, fmaf(P3.y, P3.y, P4.x * P4.x));
        float w3 = fmaf(P4.y, P4.y, fmaf(P5.x, P5.x, P5.y * P5.y));
        f2 wp01 = {w0, w1}, wp23 = {w2, w3};
#pragma unroll
        for (int j = 0; j < Q2; ++j) {
            f2 d0, d1, d2, d3;
            // t0: x0=(P0,lo) y0=(P0,hi) z0=(P1,lo) w0=(wp01,lo)
            asm("v_pk_fma_f32 %0, %1, %2, %3 op_sel:[0,0,0] op_sel_hi:[1,0,0]"
                : "=v"(d0) : "v"(sz[j]), "v"(P1), "v"(wp01));
            asm("v_pk_fma_f32 %0, %1, %2, %0 op_sel:[0,1,0] op_sel_hi:[1,1,1]"
                : "+v"(d0) : "v"(sy[j]), "v"(P0));
            asm("v_pk_fma_f32 %0, %1, %2, %0 op_sel:[0,0,0] op_sel_hi:[1,0,1]"
                : "+v"(d0) : "v"(sx[j]), "v"(P0));
            // t1: x1=(P1,hi) y1=(P2,lo) z1=(P2,hi) w1=(wp01,hi)
            asm("v_pk_fma_f32 %0, %1, %2, %3 op_sel:[0,1,1] op_sel_hi:[1,1,1]"
                : "=v"(d1) : "v"(sz[j]), "v"(P2), "v"(wp01));
            asm("v_pk_fma_f32 %0, %1, %2, %0 op_sel:[0,0,0] op_sel_hi:[1,0,1]"
                : "+v"(d1) : "v"(sy[j]), "v"(P2));
            asm("v_pk_fma_f32 %0, %1, %2, %0 op_sel:[0,1,0] op_sel_hi:[1,1,1]"
                : "+v"(d1) : "v"(sx[j]), "v"(P1));
            // t2: x2=(P3,lo) y2=(P3,hi) z2=(P4,lo) w2=(wp23,lo)
            asm("v_pk_fma_f32 %0, %1, %2, %3 op_sel:[0,0,0] op_sel_hi:[1,0,0]"
                : "=v"(d2) : "v"(sz[j]), "v"(P4), "v"(wp23));
            asm("v_pk_fma_f32 %0, %1, %2, %0 op_sel:[0,1,0] op_sel_hi:[1,1,1]"
                : "+v"(d2) : "v"(sy[j]), "v"(P3));
            asm("v_pk_fma_f32 %0, %1, %2, %0 op_sel:[0,0,0] op_sel_hi:[1,0,1]"
                : "+v"(d2) : "v"(sx[j]), "v"(P3));
            // t3: x3=(P4,hi) y3=(P5,lo) z3=(P5,hi) w3=(wp23,hi)
            asm("v_pk_fma_f32 %0, %1, %2, %3 op_sel:[0,1,1] op_sel_hi:[1,1,1]"
                : "=v"(d3) : "v"(sz[j]), "v"(P5), "v"(wp23));
            asm("v_pk_fma_f32 %0, %1, %2, %0 op_sel:[0,0,0] op_sel_hi:[1,0,1]"
                : "+v"(d3) : "v"(sy[j]), "v"(P5));
            asm("v_pk_fma_f32 %0, %1, %2, %0 op_sel:[0,1,0] op_sel_hi:[1,1,1]"
                : "+v"(d3) : "v"(sx[j]), "v"(P4));
            best[j].x = fminf(fminf(best[j].x, d0.x), d1.x);   // -> v_min3_f32
            best[j].x = fminf(fminf(best[j].x, d2.x), d3.x);
            best[j].y = fminf(fminf(best[j].y, d0.y), d1.y);
            best[j].y = fminf(fminf(best[j].y, d2.y), d3.y);
        }
    }

    // ---- epilogue: + |q|^2 (recomputed from -2q: |q|^2 = 0.25*|s|^2) ----
    unsigned int* mbase = mins + ((size_t)dir * BATCH + b) * NPTS;
#pragma unroll
    for (int j = 0; j < Q2; ++j) {
        float qa2 = 0.25f * fmaf(sx[j].x, sx[j].x, fmaf(sy[j].x, sy[j].x, sz[j].x * sz[j].x));
        float qb2 = 0.25f * fmaf(sx[j].y, sx[j].y, fmaf(sy[j].y, sy[j].y, sz[j].y * sz[j].y));
        float va = fmaxf(best[j].x + qa2, 0.0f);
        float vb = fmaxf(best[j].y + qb2, 0.0f);
        atomicMin(&mbase[qbase + (2 * j + 0) * THREADS + tid], __float_as_uint(va));
        atomicMin(&mbase[qbase + (2 * j + 1) * THREADS + tid], __float_as_uint(vb));
    }

    // ---- fused final reduction: last block to finish sums all mins ----
    if (counter) {
        __threadfence();                 // make this block's atomics agent-visible
        __syncthreads();                 // all threads' atomics issued+fenced
        __shared__ unsigned int tick;
        if (tid == 0)
            tick = __hip_atomic_fetch_add(counter, 1u, __ATOMIC_ACQ_REL,
                                          __HIP_MEMORY_SCOPE_AGENT);
        __syncthreads();
        if (tick == NBLOCKS - 1) {
            float s = 0.0f;
            for (int i = tid; i < NMINS; i += THREADS) {
                unsigned int u = __hip_atomic_load(&mins[i], __ATOMIC_RELAXED,
                                                   __HIP_MEMORY_SCOPE_AGENT);
                s += __uint_as_float(u);
            }
#pragma unroll
            for (int off = 32; off >= 1; off >>= 1)
                s += __shfl_down(s, off, 64);
            __shared__ float part[THREADS / 64];
            if ((tid & 63) == 0) part[tid >> 6] = s;
            __syncthreads();
            if (tid == 0) {
                float tot = part[0] + part[1] + part[2] + part[3];
                out[0] = tot * (1.0f / (BATCH * NPTS));
            }
        }
    }
}

// fallback (only used if ws has no room for the ticket counter)
__global__ __launch_bounds__(THREADS) void chamfer_reduce(
    const uint4* __restrict__ mins, float* __restrict__ out)
{
    const int i = blockIdx.x * THREADS + threadIdx.x;
    uint4 u = mins[i];
    float s = __uint_as_float(u.x) + __uint_as_float(u.y)
            + __uint_as_float(u.z) + __uint_as_float(u.w);
#pragma unroll
    for (int off = 32; off >= 1; off >>= 1)
        s += __shfl_down(s, off, 64);
    __shared__ float partial[THREADS / 64];
    if ((threadIdx.x & 63) == 0) partial[threadIdx.x >> 6] = s;
    __syncthreads();
    if (threadIdx.x == 0) {
        float tot = 0.0f;
#pragma unroll
        for (int w = 0; w < THREADS / 64; ++w) tot += partial[w];
        atomicAdd(out, tot * (1.0f / (BATCH * NPTS)));
    }
}

extern "C" void kernel_launch(void* const* d_in, const int* in_sizes, int n_in,
                              void* d_out, int out_size, void* d_ws, size_t ws_size,
                              hipStream_t stream) {
    const float* p1 = (const float*)d_in[0];
    const float* p2 = (const float*)d_in[1];
    unsigned int* mins = (unsigned int*)d_ws;
    float* out = (float*)d_out;
    const bool fused = ws_size >= (size_t)(NMINS + 1) * sizeof(unsigned int);
    unsigned int* counter = fused ? (mins + NMINS) : nullptr;

    chamfer_init<<<NMINS / THREADS, THREADS, 0, stream>>>(mins, counter, out);

    dim3 grid(NPTS / (THREADS * QPT), SLICES, 2 * BATCH);
    chamfer_main<<<grid, THREADS, 0, stream>>>(p1, p2, mins, counter, out);

    if (!fused)
        chamfer_reduce<<<NMINS / (4 * THREADS), THREADS, 0, stream>>>(
            (const uint4*)mins, out);
}

// Round 4
// 274.537 us; speedup vs baseline: 1.0951x; 1.0951x over previous
//
#include <hip/hip_runtime.h>

#define THREADS 256
#define QPT 8              // queries per thread (4 float2 packs)
#define Q2  (QPT / 2)
#define SLICES 64
#define NPTS 8192
#define BATCH 4
#define SLICE (NPTS / SLICES)   // 128 targets per block
#define NMINS (2 * BATCH * NPTS)            // 65536
#define NBLOCKS ((NPTS / (THREADS * QPT)) * SLICES * 2 * BATCH)  // 4*64*8 = 2048

typedef float f2 __attribute__((ext_vector_type(2)));
typedef float f4 __attribute__((ext_vector_type(4)));

// ws layout: [2][BATCH][NPTS] uint min arrays (256 KB) + 1 uint ticket counter

__global__ void chamfer_init(unsigned int* mins, unsigned int* counter) {
    int i = blockIdx.x * blockDim.x + threadIdx.x;
    mins[i] = 0x7F800000u;  // +inf
    if (i == 0 && counter) *counter = 0u;
}

__global__ __launch_bounds__(THREADS, 4) void chamfer_main(
    const float* __restrict__ p1, const float* __restrict__ p2,
    unsigned int* __restrict__ mins, unsigned int* __restrict__ counter,
    float* __restrict__ out)
{
    const int tid  = threadIdx.x;
    const int bz   = blockIdx.z;         // 0..7 : dir*4 + batch
    const int dir  = bz >> 2;
    const int b    = bz & 3;
    const int qbase = blockIdx.x * (THREADS * QPT);
    const int tbase = blockIdx.y * SLICE;

    const float* __restrict__ qsrc = (dir == 0) ? p1 : p2;
    const float* __restrict__ tsrc = (dir == 0) ? p2 : p1;

    // ---- stage transformed targets into LDS: (-2x, -2y, -2z, |t|^2) ----
    __shared__ f4 tgt[SLICE];
    {
        const float* tp = tsrc + ((size_t)b * NPTS + tbase) * 3;
        for (int k = tid; k < SLICE; k += THREADS) {
            float x = tp[k * 3 + 0];
            float y = tp[k * 3 + 1];
            float z = tp[k * 3 + 2];
            tgt[k] = f4{-2.0f * x, -2.0f * y, -2.0f * z,
                        fmaf(x, x, fmaf(y, y, z * z))};
        }
    }

    // ---- load this thread's queries, packed 2-wide ----
    f2 ax2[Q2], ay2[Q2], az2[Q2], best2[Q2];
#pragma unroll
    for (int j = 0; j < Q2; ++j) {
        const int qa = qbase + (2 * j + 0) * THREADS + tid;
        const int qb = qbase + (2 * j + 1) * THREADS + tid;
        const float* pa = qsrc + ((size_t)b * NPTS + qa) * 3;
        const float* pb = qsrc + ((size_t)b * NPTS + qb) * 3;
        ax2[j] = f2{pa[0], pb[0]};
        ay2[j] = f2{pa[1], pb[1]};
        az2[j] = f2{pa[2], pb[2]};
        best2[j] = f2{3.0e38f, 3.0e38f};
    }

    __syncthreads();

    // ---- main loop: 2 targets/iter, asm pk-FMA with op_sel broadcast ----
    // d = fma(az, -2z, |t|^2); d += ay*(-2y); d += ax*(-2x)
    // target components broadcast from the halves of the ds_read_b128 result
    // via op_sel / op_sel_hi -- zero splat movs, guaranteed v_pk_fma_f32.
    // (this exact asm passed absmax=0.0 in an earlier round)
#pragma unroll 2
    for (int m = 0; m < SLICE; m += 2) {
        f4 ta = tgt[m];
        f4 tb = tgt[m + 1];
        f2 ta_xy = __builtin_shufflevector(ta, ta, 0, 1);
        f2 ta_zw = __builtin_shufflevector(ta, ta, 2, 3);
        f2 tb_xy = __builtin_shufflevector(tb, tb, 0, 1);
        f2 tb_zw = __builtin_shufflevector(tb, tb, 2, 3);
#pragma unroll
        for (int j = 0; j < Q2; ++j) {
            f2 da, db;
            asm("v_pk_fma_f32 %0, %1, %2, %2 op_sel:[0,0,1] op_sel_hi:[1,0,1]"
                : "=v"(da) : "v"(az2[j]), "v"(ta_zw));
            asm("v_pk_fma_f32 %0, %1, %2, %0 op_sel:[0,1,0] op_sel_hi:[1,1,1]"
                : "+v"(da) : "v"(ay2[j]), "v"(ta_xy));
            asm("v_pk_fma_f32 %0, %1, %2, %0 op_sel:[0,0,0] op_sel_hi:[1,0,1]"
                : "+v"(da) : "v"(ax2[j]), "v"(ta_xy));
            asm("v_pk_fma_f32 %0, %1, %2, %2 op_sel:[0,0,1] op_sel_hi:[1,0,1]"
                : "=v"(db) : "v"(az2[j]), "v"(tb_zw));
            asm("v_pk_fma_f32 %0, %1, %2, %0 op_sel:[0,1,0] op_sel_hi:[1,1,1]"
                : "+v"(db) : "v"(ay2[j]), "v"(tb_xy));
            asm("v_pk_fma_f32 %0, %1, %2, %0 op_sel:[0,0,0] op_sel_hi:[1,0,1]"
                : "+v"(db) : "v"(ax2[j]), "v"(tb_xy));
            best2[j].x = fminf(fminf(best2[j].x, da.x), db.x);   // -> v_min3_f32
            best2[j].y = fminf(fminf(best2[j].y, da.y), db.y);
        }
    }

    // ---- epilogue: + |q|^2, clamp tiny negative from cancellation ----
    unsigned int* mbase = mins + ((size_t)dir * BATCH + b) * NPTS;
#pragma unroll
    for (int j = 0; j < Q2; ++j) {
        float qa2 = fmaf(ax2[j].x, ax2[j].x, fmaf(ay2[j].x, ay2[j].x, az2[j].x * az2[j].x));
        float qb2 = fmaf(ax2[j].y, ax2[j].y, fmaf(ay2[j].y, ay2[j].y, az2[j].y * az2[j].y));
        float va = fmaxf(best2[j].x + qa2, 0.0f);
        float vb = fmaxf(best2[j].y + qb2, 0.0f);
        atomicMin(&mbase[qbase + (2 * j + 0) * THREADS + tid], __float_as_uint(va));
        atomicMin(&mbase[qbase + (2 * j + 1) * THREADS + tid], __float_as_uint(vb));
    }

    // ---- fused final reduction: last block to finish sums all mins ----
    if (counter) {
        __threadfence();                 // make this block's atomics agent-visible
        __syncthreads();                 // all threads' atomics issued+fenced
        __shared__ unsigned int tick;
        if (tid == 0)
            tick = __hip_atomic_fetch_add(counter, 1u, __ATOMIC_ACQ_REL,
                                          __HIP_MEMORY_SCOPE_AGENT);
        __syncthreads();
        if (tick == NBLOCKS - 1) {
            float s = 0.0f;
            for (int i = tid; i < NMINS; i += THREADS) {
                unsigned int u = __hip_atomic_load(&mins[i], __ATOMIC_RELAXED,
                                                   __HIP_MEMORY_SCOPE_AGENT);
                s += __uint_as_float(u);
            }
#pragma unroll
            for (int off = 32; off >= 1; off >>= 1)
                s += __shfl_down(s, off, 64);
            __shared__ float part[THREADS / 64];
            if ((tid & 63) == 0) part[tid >> 6] = s;
            __syncthreads();
            if (tid == 0) {
                float tot = part[0] + part[1] + part[2] + part[3];
                out[0] = tot * (1.0f / (BATCH * NPTS));
            }
        }
    }
}

// fallback (only used if ws has no room for the ticket counter)
__global__ __launch_bounds__(THREADS) void chamfer_reduce(
    const uint4* __restrict__ mins, float* __restrict__ out)
{
    const int i = blockIdx.x * THREADS + threadIdx.x;
    uint4 u = mins[i];
    float s = __uint_as_float(u.x) + __uint_as_float(u.y)
            + __uint_as_float(u.z) + __uint_as_float(u.w);
#pragma unroll
    for (int off = 32; off >= 1; off >>= 1)
        s += __shfl_down(s, off, 64);
    __shared__ float partial[THREADS / 64];
    if ((threadIdx.x & 63) == 0) partial[threadIdx.x >> 6] = s;
    __syncthreads();
    if (threadIdx.x == 0) {
        float tot = 0.0f;
#pragma unroll
        for (int w = 0; w < THREADS / 64; ++w) tot += partial[w];
        atomicAdd(out, tot * (1.0f / (BATCH * NPTS)));
    }
}

extern "C" void kernel_launch(void* const* d_in, const int* in_sizes, int n_in,
                              void* d_out, int out_size, void* d_ws, size_t ws_size,
                              hipStream_t stream) {
    const float* p1 = (const float*)d_in[0];
    const float* p2 = (const float*)d_in[1];
    unsigned int* mins = (unsigned int*)d_ws;
    float* out = (float*)d_out;
    const bool fused = ws_size >= (size_t)(NMINS + 1) * sizeof(unsigned int);
    unsigned int* counter = fused ? (mins + NMINS) : nullptr;

    chamfer_init<<<NMINS / THREADS, THREADS, 0, stream>>>(mins, counter);

    // main: x = query blocks (8192/(256*8)=4), y = target slices (64), z = dir*4+batch
    dim3 grid(NPTS / (THREADS * QPT), SLICES, 2 * BATCH);
    chamfer_main<<<grid, THREADS, 0, stream>>>(p1, p2, mins, counter, out);

    if (!fused)
        chamfer_reduce<<<NMINS / (4 * THREADS), THREADS, 0, stream>>>(
            (const uint4*)mins, out);
}

// Round 5
// 96.068 us; speedup vs baseline: 3.1294x; 2.8577x over previous
//
#include <hip/hip_runtime.h>

#define THREADS 256
#define QPT 8              // queries per thread (4 float2 packs)
#define Q2  (QPT / 2)
#define SLICES 32
#define NPTS 8192
#define BATCH 4
#define SLICE (NPTS / SLICES)   // 256 targets per block
#define NMINS (2 * BATCH * NPTS)            // 65536

typedef float f2 __attribute__((ext_vector_type(2)));
typedef float f4 __attribute__((ext_vector_type(4)));

// ws layout: [2][BATCH][NPTS] uint (float bits) min arrays = 65536 entries = 256 KB

__global__ void chamfer_init(unsigned int* mins, float* out) {
    int i = blockIdx.x * blockDim.x + threadIdx.x;
    mins[i] = 0x7F800000u;  // +inf
    if (i == 0) out[0] = 0.0f;
}

__global__ __launch_bounds__(THREADS) void chamfer_main(
    const float* __restrict__ p1, const float* __restrict__ p2,
    unsigned int* __restrict__ mins)
{
    const int tid  = threadIdx.x;
    const int bz   = blockIdx.z;         // 0..7 : dir*4 + batch
    const int dir  = bz >> 2;
    const int b    = bz & 3;
    const int qbase = blockIdx.x * (THREADS * QPT);
    const int tbase = blockIdx.y * SLICE;

    const float* __restrict__ qsrc = (dir == 0) ? p1 : p2;
    const float* __restrict__ tsrc = (dir == 0) ? p2 : p1;

    // ---- stage transformed targets into LDS: (-2x, -2y, -2z, |t|^2) ----
    __shared__ f4 tgt[SLICE];
    {
        const float* tp = tsrc + ((size_t)b * NPTS + tbase) * 3;
        for (int k = tid; k < SLICE; k += THREADS) {
            float x = tp[k * 3 + 0];
            float y = tp[k * 3 + 1];
            float z = tp[k * 3 + 2];
            tgt[k] = f4{-2.0f * x, -2.0f * y, -2.0f * z,
                        fmaf(x, x, fmaf(y, y, z * z))};
        }
    }

    // ---- load this thread's queries, packed 2-wide ----
    f2 ax2[Q2], ay2[Q2], az2[Q2], best2[Q2];
#pragma unroll
    for (int j = 0; j < Q2; ++j) {
        const int qa = qbase + (2 * j + 0) * THREADS + tid;
        const int qb = qbase + (2 * j + 1) * THREADS + tid;
        const float* pa = qsrc + ((size_t)b * NPTS + qa) * 3;
        const float* pb = qsrc + ((size_t)b * NPTS + qb) * 3;
        ax2[j] = f2{pa[0], pb[0]};
        ay2[j] = f2{pa[1], pb[1]};
        az2[j] = f2{pa[2], pb[2]};
        best2[j] = f2{3.0e38f, 3.0e38f};
    }

    __syncthreads();

    // ---- main loop: 2 targets/iter, asm pk-FMA with op_sel broadcast ----
    // d = fma(az, -2z, |t|^2); d += ay*(-2y); d += ax*(-2x)
    // target components broadcast from the halves of the ds_read_b128 result
    // via op_sel / op_sel_hi -- zero splat movs, guaranteed v_pk_fma_f32.
    // (verified absmax=0.0 in round 4)
#pragma unroll 4
    for (int m = 0; m < SLICE; m += 2) {
        f4 ta = tgt[m];
        f4 tb = tgt[m + 1];
        f2 ta_xy = __builtin_shufflevector(ta, ta, 0, 1);
        f2 ta_zw = __builtin_shufflevector(ta, ta, 2, 3);
        f2 tb_xy = __builtin_shufflevector(tb, tb, 0, 1);
        f2 tb_zw = __builtin_shufflevector(tb, tb, 2, 3);
#pragma unroll
        for (int j = 0; j < Q2; ++j) {
            f2 da, db;
            asm("v_pk_fma_f32 %0, %1, %2, %2 op_sel:[0,0,1] op_sel_hi:[1,0,1]"
                : "=v"(da) : "v"(az2[j]), "v"(ta_zw));
            asm("v_pk_fma_f32 %0, %1, %2, %0 op_sel:[0,1,0] op_sel_hi:[1,1,1]"
                : "+v"(da) : "v"(ay2[j]), "v"(ta_xy));
            asm("v_pk_fma_f32 %0, %1, %2, %0 op_sel:[0,0,0] op_sel_hi:[1,0,1]"
                : "+v"(da) : "v"(ax2[j]), "v"(ta_xy));
            asm("v_pk_fma_f32 %0, %1, %2, %2 op_sel:[0,0,1] op_sel_hi:[1,0,1]"
                : "=v"(db) : "v"(az2[j]), "v"(tb_zw));
            asm("v_pk_fma_f32 %0, %1, %2, %0 op_sel:[0,1,0] op_sel_hi:[1,1,1]"
                : "+v"(db) : "v"(ay2[j]), "v"(tb_xy));
            asm("v_pk_fma_f32 %0, %1, %2, %0 op_sel:[0,0,0] op_sel_hi:[1,0,1]"
                : "+v"(db) : "v"(ax2[j]), "v"(tb_xy));
            best2[j].x = fminf(fminf(best2[j].x, da.x), db.x);   // -> v_min3_f32
            best2[j].y = fminf(fminf(best2[j].y, da.y), db.y);
        }
    }

    // ---- epilogue: + |q|^2, clamp tiny negative from cancellation ----
    unsigned int* mbase = mins + ((size_t)dir * BATCH + b) * NPTS;
#pragma unroll
    for (int j = 0; j < Q2; ++j) {
        float qa2 = fmaf(ax2[j].x, ax2[j].x, fmaf(ay2[j].x, ay2[j].x, az2[j].x * az2[j].x));
        float qb2 = fmaf(ax2[j].y, ax2[j].y, fmaf(ay2[j].y, ay2[j].y, az2[j].y * az2[j].y));
        float va = fmaxf(best2[j].x + qa2, 0.0f);
        float vb = fmaxf(best2[j].y + qb2, 0.0f);
        atomicMin(&mbase[qbase + (2 * j + 0) * THREADS + tid], __float_as_uint(va));
        atomicMin(&mbase[qbase + (2 * j + 1) * THREADS + tid], __float_as_uint(vb));
    }
}

__global__ __launch_bounds__(THREADS) void chamfer_reduce(
    const uint4* __restrict__ mins, float* __restrict__ out)
{
    const int i = blockIdx.x * THREADS + threadIdx.x;   // 64 blocks * 256 = 16384 uint4
    uint4 u = mins[i];
    float s = __uint_as_float(u.x) + __uint_as_float(u.y)
            + __uint_as_float(u.z) + __uint_as_float(u.w);
#pragma unroll
    for (int off = 32; off >= 1; off >>= 1)
        s += __shfl_down(s, off, 64);
    __shared__ float partial[THREADS / 64];
    if ((threadIdx.x & 63) == 0) partial[threadIdx.x >> 6] = s;
    __syncthreads();
    if (threadIdx.x == 0) {
        float tot = 0.0f;
#pragma unroll
        for (int w = 0; w < THREADS / 64; ++w) tot += partial[w];
        atomicAdd(out, tot * (1.0f / (BATCH * NPTS)));
    }
}

extern "C" void kernel_launch(void* const* d_in, const int* in_sizes, int n_in,
                              void* d_out, int out_size, void* d_ws, size_t ws_size,
                              hipStream_t stream) {
    const float* p1 = (const float*)d_in[0];
    const float* p2 = (const float*)d_in[1];
    unsigned int* mins = (unsigned int*)d_ws;   // 65536 uints
    float* out = (float*)d_out;

    // init mins to +inf, out to 0
    chamfer_init<<<NMINS / THREADS, THREADS, 0, stream>>>(mins, out);

    // main: x = query blocks (8192/(256*8)=4), y = target slices (32), z = dir*4+batch
    dim3 grid(NPTS / (THREADS * QPT), SLICES, 2 * BATCH);
    chamfer_main<<<grid, THREADS, 0, stream>>>(p1, p2, mins);

    // parallel reduce: 65536 mins / 4 per thread / 256 per block = 64 blocks
    chamfer_reduce<<<NMINS / (4 * THREADS), THREADS, 0, stream>>>(
        (const uint4*)mins, out);
}